// Round 5
// baseline (169.911 us; speedup 1.0000x reference)
//
#include <hip/hip_runtime.h>
#include <math.h>

#define T_TOK 16384   // 4*4096 tokens
#define NEXP  64

// Workspace layout (floats):
//   ws[0..63]   : expert load sums
//   ws[64]      : sum of z^2
//   ws[66]      : block-done counter (int)
//   ws[128 ..]  : w_t transposed gate weights [1024][64]
//
// d_out layout (floats, out_size = 65537):
//   [0, 32768)      top-2 renormalized scores [token][2]
//   [32768, 65536)  top-2 expert indices as floats [token][2]
//   [65536]         total_loss

// ---------------------------------------------------------------------------
// prep: tiled transpose gate_w [64][1024] -> w_t [1024][64]; zero accumulators
// ---------------------------------------------------------------------------
__global__ void moe_prep(const float* __restrict__ gw, float* __restrict__ ws) {
    __shared__ float tile[64][65];
    const int b = blockIdx.x;
    const int tid = threadIdx.x;         // 256
    if (b == 0 && tid < 128) ws[tid] = 0.f;
#pragma unroll
    for (int it = 0; it < 16; ++it) {
        int idx = it * 256 + tid;
        int e = idx >> 6, kk = idx & 63;
        tile[e][kk] = gw[e * 1024 + b * 64 + kk];
    }
    __syncthreads();
#pragma unroll
    for (int it = 0; it < 16; ++it) {
        int idx = it * 256 + tid;
        int kk = idx >> 6, e = idx & 63;
        ws[128 + (b * 64 + kk) * 64 + e] = tile[e][kk];
    }
}

// ---------------------------------------------------------------------------
// main: round-0 proven micro-structure (53.4 us best), with K_STEP 64 -> 256.
// R0-R4 invariant: step time ~8000 cyc vs VALU wall 2048 -> ~4-6K cyc/step of
// fixed overhead (post-barrier LDS-latency ramp + pre-barrier write drain +
// 16-wave convoy resync), paid 16x. This round pays it 4x: 4 fat steps,
// 8 barriers total (was 32). Per-CU FMA / LDS-read / LDS-write / HBM totals
// are IDENTICAL to round 0 -- pure A/B on per-step overhead.
// xbuf [64t][4q*16g*4] with the proven XOR-swizzle on the low-4 granule bits;
// wbuf [256k][64e] straight; 4t x 4e per lane; kq quarter q owns global
// k in [q*256 + s*64, +64) at step s (same ownership as round 0, so the
// 4-phase fold and everything after is bit-identical). VGPR budget ~95
// (acc16 + xa16 + wa16 + 8 prefetch f4 = 32 + addr), cap 128 via bounds.
// ---------------------------------------------------------------------------
__launch_bounds__(1024, 4)
__global__ void moe_main(const float* __restrict__ x,
                         const float* __restrict__ wt,     // [1024][64]
                         float* __restrict__ acc_ws,
                         float* __restrict__ out) {
    __shared__ float xbuf[64 * 256];     // x slab: [t 64][q 4][g 16 ^ swz][4]
    __shared__ float wbuf[256 * 64];     // w slab: [krow 256][e 64] straight
    __shared__ float sc[64 * 68];        // logits, stride 68
    __shared__ float row_inv[64];
    __shared__ float colpart[16][64];
    __shared__ int   is_last;

    const int tid  = threadIdx.x;
    const int lane = tid & 63;
    const int wv   = tid >> 6;                                   // 0..15
    const int kq   = __builtin_amdgcn_readfirstlane(wv & 3);     // k quarter
    const int tile = __builtin_amdgcn_readfirstlane(wv >> 2);    // (t,e) tile
    const int tt = tile >> 1, te = tile & 1;
    const int ta = lane >> 3;            // token-quad within tile (0..7)
    const int eb = lane & 7;             // expert-quad within tile (0..7)
    const int tok0 = blockIdx.x << 6;

    // ---- staging plan (1024 threads, 4 float4 x + 4 float4 w per step)
    // x: thread (rr, cg) stages granules q*16+cg of row rr, q=0..3.
    //    global k of granule (q, cg) at step s: q*256 + s*64 + cg*4
    const int rr = tid >> 4;             // 0..63
    const int cg = tid & 15;
    const float* gx = x + (((size_t)(tok0 + rr)) << 10) + (cg << 2);
    const int xsw = (cg ^ (rr & 15)) << 2;           // swizzled granule slot
    // w: thread stages rows r = rr + 64q; row r holds global k-row
    //    (r>>6)*256 + s*64 + (r&63)
    const float* gwb = wt + (rr << 6) + (cg << 2);
    const int wlo = (rr << 6) + (cg << 2);           // + q*4096 (floats)

    float acc[16];
#pragma unroll
    for (int e = 0; e < 16; ++e) acc[e] = 0.f;

    // ---- per-lane read bases
    const int t0 = (tt << 5) + (ta << 2);           // token base within block
    const float* xq0 = xbuf + ((t0 + 0) << 8) + (kq << 6);
    const float* xq1 = xbuf + ((t0 + 1) << 8) + (kq << 6);
    const float* xq2 = xbuf + ((t0 + 2) << 8) + (kq << 6);
    const float* xq3 = xbuf + ((t0 + 3) << 8) + (kq << 6);
    const int c0 = (t0 + 0) & 15, c1 = (t0 + 1) & 15;
    const int c2 = (t0 + 2) & 15, c3 = (t0 + 3) & 15;
    const int ebase = (te << 5) + (eb << 2);        // expert base within block
    const float* wbase = wbuf + (kq << 12) + ebase; // + (m*4+u)*64 (imm)

    // prologue prefetch of step 0 (4 + 4 named float4 regs)
    float4 px0 = *(const float4*)(gx);
    float4 px1 = *(const float4*)(gx + 256);
    float4 px2 = *(const float4*)(gx + 512);
    float4 px3 = *(const float4*)(gx + 768);
    float4 pw0 = *(const float4*)(gwb);
    float4 pw1 = *(const float4*)(gwb + 16384);
    float4 pw2 = *(const float4*)(gwb + 32768);
    float4 pw3 = *(const float4*)(gwb + 49152);

#pragma unroll 1
    for (int s = 0; s < 4; ++s) {
        __syncthreads();                            // bufs free
        {   // x stores: row rr, slots q*64 + swz(cg)
            float* xr = xbuf + (rr << 8) + xsw;
            *(float4*)(xr)       = px0;
            *(float4*)(xr + 64)  = px1;
            *(float4*)(xr + 128) = px2;
            *(float4*)(xr + 192) = px3;
            float* wr = wbuf + wlo;
            *(float4*)(wr)         = pw0;
            *(float4*)(wr + 4096)  = pw1;
            *(float4*)(wr + 8192)  = pw2;
            *(float4*)(wr + 12288) = pw3;
        }
        __syncthreads();                            // bufs ready
        if (s < 3) {                                // prefetch next step
            const int xo = (s + 1) << 6;            // +64 floats k
            px0 = *(const float4*)(gx + xo);
            px1 = *(const float4*)(gx + xo + 256);
            px2 = *(const float4*)(gx + xo + 512);
            px3 = *(const float4*)(gx + xo + 768);
            const int wo = (s + 1) << 12;           // +64 k-rows * 64
            pw0 = *(const float4*)(gwb + wo);
            pw1 = *(const float4*)(gwb + wo + 16384);
            pw2 = *(const float4*)(gwb + wo + 32768);
            pw3 = *(const float4*)(gwb + wo + 49152);
        }
#pragma unroll
        for (int m = 0; m < 16; ++m) {
            float4 xf0 = *(const float4*)(xq0 + (((m ^ c0) & 15) << 2));
            float4 xf1 = *(const float4*)(xq1 + (((m ^ c1) & 15) << 2));
            float4 xf2 = *(const float4*)(xq2 + (((m ^ c2) & 15) << 2));
            float4 xf3 = *(const float4*)(xq3 + (((m ^ c3) & 15) << 2));
            const float* wq = wbase + (m << 8);
            float4 wf0 = *(const float4*)(wq);
            float4 wf1 = *(const float4*)(wq + 64);
            float4 wf2 = *(const float4*)(wq + 128);
            float4 wf3 = *(const float4*)(wq + 192);
            float xa[16] = {xf0.x, xf0.y, xf0.z, xf0.w,
                            xf1.x, xf1.y, xf1.z, xf1.w,
                            xf2.x, xf2.y, xf2.z, xf2.w,
                            xf3.x, xf3.y, xf3.z, xf3.w};
            float wa[16] = {wf0.x, wf0.y, wf0.z, wf0.w,
                            wf1.x, wf1.y, wf1.z, wf1.w,
                            wf2.x, wf2.y, wf2.z, wf2.w,
                            wf3.x, wf3.y, wf3.z, wf3.w};
#pragma unroll
            for (int i = 0; i < 4; ++i)
#pragma unroll
                for (int u = 0; u < 4; ++u) {
                    float xv = xa[(i << 2) + u];
#pragma unroll
                    for (int j = 0; j < 4; ++j)
                        acc[(i << 2) + j] = fmaf(xv, wa[(u << 2) + j], acc[(i << 2) + j]);
                }
        }
    }

    // ---- combine 4 k-quarter partials into sc (barrier chain over kq)
    if (kq == 0) {
#pragma unroll
        for (int i = 0; i < 4; ++i) {
            float4 v = make_float4(acc[(i << 2)], acc[(i << 2) + 1],
                                   acc[(i << 2) + 2], acc[(i << 2) + 3]);
            *(float4*)(sc + (t0 + i) * 68 + ebase) = v;
        }
    }
    __syncthreads();
    if (kq == 1) {
#pragma unroll
        for (int i = 0; i < 4; ++i) {
            float4 o = *(float4*)(sc + (t0 + i) * 68 + ebase);
            o.x += acc[(i << 2)];     o.y += acc[(i << 2) + 1];
            o.z += acc[(i << 2) + 2]; o.w += acc[(i << 2) + 3];
            *(float4*)(sc + (t0 + i) * 68 + ebase) = o;
        }
    }
    __syncthreads();
    if (kq == 2) {
#pragma unroll
        for (int i = 0; i < 4; ++i) {
            float4 o = *(float4*)(sc + (t0 + i) * 68 + ebase);
            o.x += acc[(i << 2)];     o.y += acc[(i << 2) + 1];
            o.z += acc[(i << 2) + 2]; o.w += acc[(i << 2) + 3];
            *(float4*)(sc + (t0 + i) * 68 + ebase) = o;
        }
    }
    __syncthreads();
    if (kq == 3) {
#pragma unroll
        for (int i = 0; i < 4; ++i) {
            float4 o = *(float4*)(sc + (t0 + i) * 68 + ebase);
            o.x += acc[(i << 2)];     o.y += acc[(i << 2) + 1];
            o.z += acc[(i << 2) + 2]; o.w += acc[(i << 2) + 3];
            *(float4*)(sc + (t0 + i) * 68 + ebase) = o;
        }
    }
    __syncthreads();

    // ---- per-token epilogue (serial, proven absmax 0)
    if (tid < 64) {
        const int r = tid;
        const float* srow = sc + r * 68;
        float v1 = -1e30f, v2 = -1e30f;
        int i1 = 0, i2 = 0;
        for (int j = 0; j < 64; ++j) {
            float l = srow[j];
            if (l > v1)      { v2 = v1; i2 = i1; v1 = l; i1 = j; }
            else if (l > v2) { v2 = l; i2 = j; }
        }
        float m = v1;
        float ssum = 0.f;
        for (int j = 0; j < 64; ++j) {
            float ev = expf(srow[j] - m);
            ssum += ev;
            sc[r * 68 + j] = ev;
        }
        float inv = 1.f / ssum;
        row_inv[r] = inv;
        float z = m + logf(ssum);
        float zsq = z * z;
#pragma unroll
        for (int off = 32; off > 0; off >>= 1) zsq += __shfl_down(zsq, off);
        if (lane == 0) atomicAdd(acc_ws + 64, zsq);

        float p1s = inv;                        // exp(v1-m) == 1
        float p2s = expf(v2 - m) * inv;
        float bb  = expf(p2s - p1s);
        float s1 = 1.f / (1.f + bb);
        float s2 = bb * s1;
        int t = tok0 + r;
        out[2 * t]     = s1;
        out[2 * t + 1] = s2;
        out[2 * T_TOK + 2 * t]     = (float)i1;
        out[2 * T_TOK + 2 * t + 1] = (float)i2;
    }
    __syncthreads();

    // ---- expert load column sums (16 row-groups of 4 rows)
    {
        int e  = tid & 63;
        int rg = tid >> 6;                      // 0..15
        float sum = 0.f;
#pragma unroll
        for (int r2 = 0; r2 < 4; ++r2) {
            int row = (rg << 2) + r2;
            sum += sc[row * 68 + e] * row_inv[row];
        }
        colpart[rg][e] = sum;
    }
    __syncthreads();
    if (tid < 64) {
        float tot = 0.f;
#pragma unroll
        for (int rg = 0; rg < 16; ++rg) tot += colpart[rg][tid];
        atomicAdd(acc_ws + tid, tot);           // device-scope
    }

    // ---- last-block finalize
    __syncthreads();
    if (tid == 0) {
        __threadfence();
        int old = __hip_atomic_fetch_add((int*)(acc_ws + 66), 1,
                                         __ATOMIC_ACQ_REL, __HIP_MEMORY_SCOPE_AGENT);
        is_last = (old == 255) ? 1 : 0;
    }
    __syncthreads();
    if (is_last && tid < 64) {
        __threadfence();
        float load = __hip_atomic_load(acc_ws + tid, __ATOMIC_RELAXED,
                                       __HIP_MEMORY_SCOPE_AGENT) * (1.f / 16384.f);
        float d = load - (1.f / 64.f);
        float v = d * d;
#pragma unroll
        for (int off = 32; off > 0; off >>= 1) v += __shfl_down(v, off);
        if (tid == 0) {
            float zsum = __hip_atomic_load(acc_ws + 64, __ATOMIC_RELAXED,
                                           __HIP_MEMORY_SCOPE_AGENT);
            float lb = 0.01f * 64.f * v;
            float zl = 1e-4f * zsum * (1.f / 16384.f);
            out[4 * T_TOK] = lb + zl;
        }
    }
}

extern "C" void kernel_launch(void* const* d_in, const int* in_sizes, int n_in,
                              void* d_out, int out_size, void* d_ws, size_t ws_size,
                              hipStream_t stream) {
    const float* x  = (const float*)d_in[0];   // [4,4096,1024] fp32
    const float* gw = (const float*)d_in[1];   // [64,1024] fp32
    float* out = (float*)d_out;                // 65537 fp32
    float* ws  = (float*)d_ws;

    moe_prep<<<16, 256, 0, stream>>>(gw, ws);
    moe_main<<<256, 1024, 0, stream>>>(x, ws + 128, ws, out);
}